// Round 8
// baseline (303.139 us; speedup 1.0000x reference)
//
#include <hip/hip_runtime.h>

#define NN 50000
#define FF 128
constexpr int NBF2 = NN * 256;   // bf16 elements of x0b, layout [n][b][f]
constexpr int CAP  = 64;         // edge-bucket capacity per node (Poisson(10): safe)
constexpr int CSTR = 16;         // cursor stride (ints): 1 counter per 64B line
constexpr int NPB  = 8;          // nodes per block (2 per wave)
constexpr int XCP = 256 + 8;     // xc row pitch (bf16)
constexpr int HSP = 128 + 8;     // hs row pitch (bf16)

typedef __attribute__((ext_vector_type(4))) short short4v;
typedef __attribute__((ext_vector_type(8))) short short8;
typedef __attribute__((ext_vector_type(4))) float floatx4;

__device__ __forceinline__ unsigned short f2bf(float x) {
    unsigned int u = __float_as_uint(x);
    unsigned int r = (u + 0x7fff + ((u >> 16) & 1)) >> 16;  // RNE, no NaNs here
    return (unsigned short)r;
}
__device__ __forceinline__ float bf2f(short x) {
    return __uint_as_float(((unsigned int)(unsigned short)x) << 16);
}

// ---- Bucket-fill edges + convert x0/w0/w1 to bf16 (one kernel) ----
__global__ __launch_bounds__(256)
void convert_fill(const int* __restrict__ dst, const int* __restrict__ src, int E,
                  const float* __restrict__ x0,
                  const float* __restrict__ w0, const float* __restrict__ w1,
                  int* __restrict__ cursor, unsigned short* __restrict__ esrc,
                  unsigned short* __restrict__ x0b,
                  unsigned short* __restrict__ w0b, unsigned short* __restrict__ w1b) {
    int i = blockIdx.x * 256 + threadIdx.x;
    if (i < E) {
        int d = dst[i];
        int pos = atomicAdd(&cursor[d * CSTR], 1);
        if (pos < CAP) esrc[d * CAP + pos] = (unsigned short)src[i];
    }
    // x0 [b][n][f] fp32 -> x0b [n][b][f] bf16
    int stride = gridDim.x * 256;
    for (int p = i; p < NBF2 / 4; p += stride) {
        int v0 = p * 4;
        int n = v0 >> 8;
        int b = (v0 >> 7) & 1;
        int f = v0 & 127;
        floatx4 in = __builtin_nontemporal_load((const floatx4*)&x0[(b * NN + n) * FF + f]);
        short4v o = { (short)f2bf(in.x), (short)f2bf(in.y), (short)f2bf(in.z), (short)f2bf(in.w) };
        *(short4v*)&x0b[v0] = o;
    }
    if (i < 128 * 256) w0b[i] = f2bf(w0[i]);
    if (i < 128 * 128) w1b[i] = f2bf(w1[i]);
}

// ---------------- Fused reduce + MFMA MLP ----------------
__global__ __launch_bounds__(256, 6)
void fused_gcn(const unsigned short* __restrict__ x0b,
               const int* __restrict__ deg,      // = cursor (stride CSTR) after fill
               const unsigned short* __restrict__ esrc,
               const unsigned short* __restrict__ w0b,
               const float* __restrict__ b0,
               const unsigned short* __restrict__ w1b,
               const float* __restrict__ b1,
               float* __restrict__ out) {
    __shared__ unsigned short xc[16 * XCP];   // 8.4 KB
    __shared__ unsigned short hs[16 * HSP];   // 4.35 KB -> 12.8 KB total

    int t = threadIdx.x;
    int q = t >> 6;        // wave id (0..3)
    int l = t & 63;        // lane
    int n0 = blockIdx.x * NPB;
    int nA = n0 + q * 2;   // wave q owns nodes nA, nA+1
    int nB = nA + 1;

    bool hi = (l >= 32);        // hi lanes serve odd edges of each pair
    int fo8 = (l & 31) * 8;     // bf16 element offset within 256-elem row
    const float NEG_INF = __int_as_float(0xFF800000);

    // Bucket loads: lane l holds edge l's src id (only lanes < deg are consumed)
    int vA = esrc[nA * CAP + l];
    int vB = esrc[nB * CAP + l];
    int dA = min(__builtin_amdgcn_readfirstlane(deg[nA * CSTR]), CAP);
    int dB = min(__builtin_amdgcn_readfirstlane(deg[nB * CSTR]), CAP);
    int dT = dA + dB;

    float SA0=0,SA1=0,SA2=0,SA3=0,SA4=0,SA5=0,SA6=0,SA7=0;
    float SB0=0,SB1=0,SB2=0,SB3=0,SB4=0,SB5=0,SB6=0,SB7=0;
    float MA0=NEG_INF,MA1=NEG_INF,MA2=NEG_INF,MA3=NEG_INF;
    float MA4=NEG_INF,MA5=NEG_INF,MA6=NEG_INF,MA7=NEG_INF;
    float MB0=NEG_INF,MB1=NEG_INF,MB2=NEG_INF,MB3=NEG_INF;
    float MB4=NEG_INF,MB5=NEG_INF,MB6=NEG_INF,MB7=NEG_INF;

#define SRCLANE(e) ( (e) < dA ? __builtin_amdgcn_readlane(vA, (e)) \
                              : __builtin_amdgcn_readlane(vB, (e) - dA) )

#define ACC8A(r) { \
    float v0=bf2f(r[0]),v1=bf2f(r[1]),v2=bf2f(r[2]),v3=bf2f(r[3]); \
    float v4=bf2f(r[4]),v5=bf2f(r[5]),v6=bf2f(r[6]),v7=bf2f(r[7]); \
    SA0+=v0;SA1+=v1;SA2+=v2;SA3+=v3;SA4+=v4;SA5+=v5;SA6+=v6;SA7+=v7; \
    MA0=fmaxf(MA0,v0);MA1=fmaxf(MA1,v1);MA2=fmaxf(MA2,v2);MA3=fmaxf(MA3,v3); \
    MA4=fmaxf(MA4,v4);MA5=fmaxf(MA5,v5);MA6=fmaxf(MA6,v6);MA7=fmaxf(MA7,v7); }

#define ACC8B(r) { \
    float v0=bf2f(r[0]),v1=bf2f(r[1]),v2=bf2f(r[2]),v3=bf2f(r[3]); \
    float v4=bf2f(r[4]),v5=bf2f(r[5]),v6=bf2f(r[6]),v7=bf2f(r[7]); \
    SB0+=v0;SB1+=v1;SB2+=v2;SB3+=v3;SB4+=v4;SB5+=v5;SB6+=v6;SB7+=v7; \
    MB0=fmaxf(MB0,v0);MB1=fmaxf(MB1,v1);MB2=fmaxf(MB2,v2);MB3=fmaxf(MB3,v3); \
    MB4=fmaxf(MB4,v4);MB5=fmaxf(MB5,v5);MB6=fmaxf(MB6,v6);MB7=fmaxf(MB7,v7); }

// one dwordx4 wave-instruction = 2 edges of the combined A+B stream
#define PAIR_LOAD(e, rname) \
    int ue##rname = SRCLANE(e); \
    int uo##rname = SRCLANE((e) + 1); \
    int us##rname = hi ? uo##rname : ue##rname; \
    short8 rname = *(const short8*)&x0b[(us##rname << 8) + fo8];

#define ACC_PAIR(e, rname) { \
    if ((e) + 1 < dA)      { ACC8A(rname) } \
    else if ((e) >= dA)    { ACC8B(rname) } \
    else { if (!hi) { ACC8A(rname) } else { ACC8B(rname) } } }

    int kk = 0;
    for (; kk + 11 < dT; kk += 12) {   // 6 pair-loads in flight (12 edges)
        PAIR_LOAD(kk + 0,  ra) PAIR_LOAD(kk + 2,  rb) PAIR_LOAD(kk + 4,  rc)
        PAIR_LOAD(kk + 6,  rd) PAIR_LOAD(kk + 8,  re) PAIR_LOAD(kk + 10, rf)
        ACC_PAIR(kk + 0,  ra) ACC_PAIR(kk + 2,  rb) ACC_PAIR(kk + 4,  rc)
        ACC_PAIR(kk + 6,  rd) ACC_PAIR(kk + 8,  re) ACC_PAIR(kk + 10, rf)
    }
    for (; kk + 3 < dT; kk += 4) {
        PAIR_LOAD(kk, ra) PAIR_LOAD(kk + 2, rb)
        ACC_PAIR(kk, ra) ACC_PAIR(kk + 2, rb)
    }
    if (kk + 1 < dT) {
        PAIR_LOAD(kk, ra)
        ACC_PAIR(kk, ra)
        kk += 2;
    }
    if (kk < dT) {                     // single tail edge: lo half only
        int ut = SRCLANE(dT - 1);
        short8 rt = *(const short8*)&x0b[(ut << 8) + fo8];
        if (dT - 1 < dA) { if (!hi) { ACC8A(rt) } }
        else             { if (!hi) { ACC8B(rt) } }
    }
#undef ACC_PAIR
#undef PAIR_LOAD
#undef SRCLANE

    // combine even/odd halves across the 32-lane boundary
    { float o;
      o=__shfl_xor(SA0,32); SA0+=o; o=__shfl_xor(SA1,32); SA1+=o;
      o=__shfl_xor(SA2,32); SA2+=o; o=__shfl_xor(SA3,32); SA3+=o;
      o=__shfl_xor(SA4,32); SA4+=o; o=__shfl_xor(SA5,32); SA5+=o;
      o=__shfl_xor(SA6,32); SA6+=o; o=__shfl_xor(SA7,32); SA7+=o;
      o=__shfl_xor(MA0,32); MA0=fmaxf(MA0,o); o=__shfl_xor(MA1,32); MA1=fmaxf(MA1,o);
      o=__shfl_xor(MA2,32); MA2=fmaxf(MA2,o); o=__shfl_xor(MA3,32); MA3=fmaxf(MA3,o);
      o=__shfl_xor(MA4,32); MA4=fmaxf(MA4,o); o=__shfl_xor(MA5,32); MA5=fmaxf(MA5,o);
      o=__shfl_xor(MA6,32); MA6=fmaxf(MA6,o); o=__shfl_xor(MA7,32); MA7=fmaxf(MA7,o);
      o=__shfl_xor(SB0,32); SB0+=o; o=__shfl_xor(SB1,32); SB1+=o;
      o=__shfl_xor(SB2,32); SB2+=o; o=__shfl_xor(SB3,32); SB3+=o;
      o=__shfl_xor(SB4,32); SB4+=o; o=__shfl_xor(SB5,32); SB5+=o;
      o=__shfl_xor(SB6,32); SB6+=o; o=__shfl_xor(SB7,32); SB7+=o;
      o=__shfl_xor(MB0,32); MB0=fmaxf(MB0,o); o=__shfl_xor(MB1,32); MB1=fmaxf(MB1,o);
      o=__shfl_xor(MB2,32); MB2=fmaxf(MB2,o); o=__shfl_xor(MB3,32); MB3=fmaxf(MB3,o);
      o=__shfl_xor(MB4,32); MB4=fmaxf(MB4,o); o=__shfl_xor(MB5,32); MB5=fmaxf(MB5,o);
      o=__shfl_xor(MB6,32); MB6=fmaxf(MB6,o); o=__shfl_xor(MB7,32); MB7=fmaxf(MB7,o); }

#define FINAL_N(g, nn, dgx, S0,S1,S2,S3,S4,S5,S6,S7, M0,M1,M2,M3,M4,M5,M6,M7) \
    if (!hi) { \
        float e0,e1,e2,e3,e4,e5,e6,e7, a0,a1,a2,a3,a4,a5,a6,a7; \
        if (dgx > 0) { \
            float inv = 1.0f / (float)dgx; \
            e0=S0*inv;e1=S1*inv;e2=S2*inv;e3=S3*inv;e4=S4*inv;e5=S5*inv;e6=S6*inv;e7=S7*inv; \
            a0=M0;a1=M1;a2=M2;a3=M3;a4=M4;a5=M5;a6=M6;a7=M7; \
        } else { \
            short8 rr = *(const short8*)&x0b[((nn) << 8) + fo8]; \
            e0=a0=bf2f(rr[0]); e1=a1=bf2f(rr[1]); e2=a2=bf2f(rr[2]); e3=a3=bf2f(rr[3]); \
            e4=a4=bf2f(rr[4]); e5=a5=bf2f(rr[5]); e6=a6=bf2f(rr[6]); e7=a7=bf2f(rr[7]); \
        } \
        int row = (q * 2 + (g)) * 2 + (l >> 4); \
        int fb  = (l & 15) * 8; \
        short8 mv = { (short)f2bf(e0),(short)f2bf(e1),(short)f2bf(e2),(short)f2bf(e3), \
                      (short)f2bf(e4),(short)f2bf(e5),(short)f2bf(e6),(short)f2bf(e7) }; \
        short8 av = { (short)f2bf(a0),(short)f2bf(a1),(short)f2bf(a2),(short)f2bf(a3), \
                      (short)f2bf(a4),(short)f2bf(a5),(short)f2bf(a6),(short)f2bf(a7) }; \
        *(short8*)&xc[row * XCP + fb]       = mv; \
        *(short8*)&xc[row * XCP + 128 + fb] = av; \
    }
    FINAL_N(0, nA, dA, SA0,SA1,SA2,SA3,SA4,SA5,SA6,SA7, MA0,MA1,MA2,MA3,MA4,MA5,MA6,MA7)
    FINAL_N(1, nB, dB, SB0,SB1,SB2,SB3,SB4,SB5,SB6,SB7, MB0,MB1,MB2,MB3,MB4,MB5,MB6,MB7)
#undef FINAL_N
#undef ACC8A
#undef ACC8B
    __syncthreads();

    // ---- MFMA MLP: 16 rows x 128 cols; wave q owns 32 cols ----
    int m    = l & 15;
    int quad = l >> 4;
    int colbase = q * 32;

    floatx4 acc[2];
#pragma unroll
    for (int ct = 0; ct < 2; ++ct) acc[ct] = (floatx4){0.f, 0.f, 0.f, 0.f};
#pragma unroll
    for (int ks = 0; ks < 8; ++ks) {
        short8 a = *(const short8*)&xc[m * XCP + ks * 32 + quad * 8];
#pragma unroll
        for (int ct = 0; ct < 2; ++ct) {
            short8 bfr = *(const short8*)&w0b[(colbase + ct * 16 + m) * 256 + ks * 32 + quad * 8];
            acc[ct] = __builtin_amdgcn_mfma_f32_16x16x32_bf16(a, bfr, acc[ct], 0, 0, 0);
        }
    }
#pragma unroll
    for (int ct = 0; ct < 2; ++ct) {
        int col = colbase + ct * 16 + m;
        float bias = b0[col];
#pragma unroll
        for (int r = 0; r < 4; ++r) {
            int row = quad * 4 + r;
            hs[row * HSP + col] = f2bf(fmaxf(acc[ct][r] + bias, 0.0f));
        }
    }
    __syncthreads();

    floatx4 acc2[2];
#pragma unroll
    for (int ct = 0; ct < 2; ++ct) acc2[ct] = (floatx4){0.f, 0.f, 0.f, 0.f};
#pragma unroll
    for (int ks = 0; ks < 4; ++ks) {
        short8 a = *(const short8*)&hs[m * HSP + ks * 32 + quad * 8];
#pragma unroll
        for (int ct = 0; ct < 2; ++ct) {
            short8 bfr = *(const short8*)&w1b[(colbase + ct * 16 + m) * 128 + ks * 32 + quad * 8];
            acc2[ct] = __builtin_amdgcn_mfma_f32_16x16x32_bf16(a, bfr, acc2[ct], 0, 0, 0);
        }
    }
#pragma unroll
    for (int ct = 0; ct < 2; ++ct) {
        int col = colbase + ct * 16 + m;
        float bias = b1[col];
#pragma unroll
        for (int r = 0; r < 4; ++r) {
            int row = quad * 4 + r;
            int n  = n0 + (row >> 1);
            int b2 = row & 1;
            // residual from bf16 x0b (saves re-reading fp32 x0; adds <=2^-9*|x| quant error)
            float xv = bf2f((short)x0b[(n << 8) + (b2 << 7) + col]);
            out[(b2 * NN + n) * FF + col] = xv + bias + acc2[ct][r];
        }
    }
}

extern "C" void kernel_launch(void* const* d_in, const int* in_sizes, int n_in,
                              void* d_out, int out_size, void* d_ws, size_t ws_size,
                              hipStream_t stream) {
    const float* x0  = (const float*)d_in[0];
    const int*   dst = (const int*)d_in[1];
    const int*   src = (const int*)d_in[2];
    const float* w0  = (const float*)d_in[3];
    const float* b0  = (const float*)d_in[4];
    const float* w1  = (const float*)d_in[5];
    const float* b1  = (const float*)d_in[6];
    float* out = (float*)d_out;
    int E = in_sizes[1];

    // ws layout: cursor (NN*CSTR ints, padded) | esrc (NN*CAP ushort) | x0b | w0b | w1b
    int* cursor = (int*)d_ws;
    unsigned short* esrc = (unsigned short*)(cursor + (size_t)NN * CSTR);
    unsigned short* x0b  = esrc + (size_t)NN * CAP;
    unsigned short* w0b  = x0b + NBF2;
    unsigned short* w1b  = w0b + 128 * 256;

    int eb = (E + 255) / 256;

    (void)hipMemsetAsync(cursor, 0, (size_t)NN * CSTR * sizeof(int), stream);
    convert_fill<<<eb, 256, 0, stream>>>(dst, src, E, x0, w0, w1, cursor, esrc, x0b, w0b, w1b);
    fused_gcn<<<NN / NPB, 256, 0, stream>>>(x0b, cursor, esrc, w0b, b0, w1b, b1, out);
}

// Round 9
// 245.222 us; speedup vs baseline: 1.2362x; 1.2362x over previous
//
#include <hip/hip_runtime.h>

#define NN 50000
#define FF 128
constexpr int NBF2 = NN * 256;   // bf16 elements of x0b, layout [n][b][f]
constexpr int CAP  = 64;         // edge-bucket capacity per node (Poisson(10): safe)
constexpr int CSTR = 4;          // cursor stride (ints): 4 counters per 64B line
constexpr int NPB  = 8;          // nodes per block (2 per wave)
constexpr int XCP = 256 + 8;     // xc row pitch (bf16)
constexpr int HSP = 128 + 8;     // hs row pitch (bf16)

typedef __attribute__((ext_vector_type(4))) short short4v;
typedef __attribute__((ext_vector_type(8))) short short8;
typedef __attribute__((ext_vector_type(4))) float floatx4;

__device__ __forceinline__ unsigned short f2bf(float x) {
    unsigned int u = __float_as_uint(x);
    unsigned int r = (u + 0x7fff + ((u >> 16) & 1)) >> 16;  // RNE, no NaNs here
    return (unsigned short)r;
}
__device__ __forceinline__ float bf2f(short x) {
    return __uint_as_float(((unsigned int)(unsigned short)x) << 16);
}

// ---- Bucket-fill edges + convert x0/w0/w1 to bf16 (one kernel) ----
__global__ __launch_bounds__(256)
void convert_fill(const int* __restrict__ dst, const int* __restrict__ src, int E,
                  const float* __restrict__ x0,
                  const float* __restrict__ w0, const float* __restrict__ w1,
                  int* __restrict__ cursor, unsigned short* __restrict__ esrc,
                  unsigned short* __restrict__ x0b,
                  unsigned short* __restrict__ w0b, unsigned short* __restrict__ w1b) {
    int i = blockIdx.x * 256 + threadIdx.x;
    if (i < E) {
        int d = dst[i];
        int pos = atomicAdd(&cursor[d * CSTR], 1);
        if (pos < CAP) esrc[d * CAP + pos] = (unsigned short)src[i];
    }
    // x0 [b][n][f] fp32 -> x0b [n][b][f] bf16; nontemporal read (keep L3 for x0b)
    int stride = gridDim.x * 256;
    for (int p = i; p < NBF2 / 4; p += stride) {
        int v0 = p * 4;
        int n = v0 >> 8;
        int b = (v0 >> 7) & 1;
        int f = v0 & 127;
        floatx4 in = __builtin_nontemporal_load((const floatx4*)&x0[(b * NN + n) * FF + f]);
        short4v o = { (short)f2bf(in.x), (short)f2bf(in.y), (short)f2bf(in.z), (short)f2bf(in.w) };
        *(short4v*)&x0b[v0] = o;
    }
    if (i < 128 * 256) w0b[i] = f2bf(w0[i]);
    if (i < 128 * 128) w1b[i] = f2bf(w1[i]);
}

// ---------------- Fused reduce + MFMA MLP ----------------
__global__ __launch_bounds__(256, 8)
void fused_gcn(const unsigned short* __restrict__ x0b,
               const float* __restrict__ x0,
               const int* __restrict__ deg,      // = cursor (stride CSTR) after fill
               const unsigned short* __restrict__ esrc,
               const unsigned short* __restrict__ w0b,
               const float* __restrict__ b0,
               const unsigned short* __restrict__ w1b,
               const float* __restrict__ b1,
               float* __restrict__ out) {
    __shared__ unsigned short xc[16 * XCP];   // 8.4 KB
    __shared__ unsigned short hs[16 * HSP];   // 4.35 KB -> 12.8 KB total

    int t = threadIdx.x;
    int q = t >> 6;        // wave id (0..3)
    int l = t & 63;        // lane
    int n0 = blockIdx.x * NPB;
    int nA = n0 + q * 2;   // wave q owns nodes nA, nA+1
    int nB = nA + 1;

    bool hi = (l >= 32);        // hi lanes serve odd edges of each pair
    int fo8 = (l & 31) * 8;     // bf16 element offset within 256-elem row
    const float NEG_INF = __int_as_float(0xFF800000);

    // ---- Early epilogue prefetch: residual x0 values (gather-independent) ----
    // Mapping matches the epilogue store: m=l&15, quad=l>>4, colbase=q*32.
    int m    = l & 15;
    int quad = l >> 4;
    int colbase = q * 32;
    float xp0,xp1,xp2,xp3,xp4,xp5,xp6,xp7;
    {
#define PRE(ct, r, dstv) { \
        int row = quad * 4 + (r); \
        int n  = n0 + (row >> 1); \
        int b2 = row & 1; \
        int oi = (b2 * NN + n) * FF + colbase + (ct) * 16 + m; \
        dstv = __builtin_nontemporal_load(&x0[oi]); }
        PRE(0,0,xp0) PRE(0,1,xp1) PRE(0,2,xp2) PRE(0,3,xp3)
        PRE(1,0,xp4) PRE(1,1,xp5) PRE(1,2,xp6) PRE(1,3,xp7)
#undef PRE
    }

    // Bucket loads: lane l holds edge l's src id (only lanes < deg are consumed)
    int vA = esrc[nA * CAP + l];
    int vB = esrc[nB * CAP + l];
    int dA = min(__builtin_amdgcn_readfirstlane(deg[nA * CSTR]), CAP);
    int dB = min(__builtin_amdgcn_readfirstlane(deg[nB * CSTR]), CAP);

#define ACC8(r, S0,S1,S2,S3,S4,S5,S6,S7, M0,M1,M2,M3,M4,M5,M6,M7) { \
    float v0=bf2f(r[0]),v1=bf2f(r[1]),v2=bf2f(r[2]),v3=bf2f(r[3]); \
    float v4=bf2f(r[4]),v5=bf2f(r[5]),v6=bf2f(r[6]),v7=bf2f(r[7]); \
    S0+=v0;S1+=v1;S2+=v2;S3+=v3;S4+=v4;S5+=v5;S6+=v6;S7+=v7; \
    M0=fmaxf(M0,v0);M1=fmaxf(M1,v1);M2=fmaxf(M2,v2);M3=fmaxf(M3,v3); \
    M4=fmaxf(M4,v4);M5=fmaxf(M5,v5);M6=fmaxf(M6,v6);M7=fmaxf(M7,v7); }

// one dwordx4 wave-instruction = 2 edges: lo lanes edge k, hi lanes edge k+1
#define PAIR_LOAD(vv, k, rname) \
    int ue##rname = __builtin_amdgcn_readlane(vv, (k));     ue##rname = (ue##rname < NN) ? ue##rname : 0; \
    int uo##rname = __builtin_amdgcn_readlane(vv, (k) + 1); uo##rname = (uo##rname < NN) ? uo##rname : 0; \
    int us##rname = hi ? uo##rname : ue##rname; \
    short8 rname = *(const short8*)&x0b[(us##rname << 8) + fo8];

#define GATHER_NODE(vv, dd, nn, g) { \
    float S0=0,S1=0,S2=0,S3=0,S4=0,S5=0,S6=0,S7=0; \
    float M0=NEG_INF,M1=NEG_INF,M2=NEG_INF,M3=NEG_INF; \
    float M4=NEG_INF,M5=NEG_INF,M6=NEG_INF,M7=NEG_INF; \
    int kk = 0; \
    for (; kk + 7 < dd; kk += 8) {          /* 4 pair-loads in flight, 8 edges */ \
        PAIR_LOAD(vv, kk,     ra) PAIR_LOAD(vv, kk + 2, rb) \
        PAIR_LOAD(vv, kk + 4, rc) PAIR_LOAD(vv, kk + 6, rd) \
        ACC8(ra, S0,S1,S2,S3,S4,S5,S6,S7, M0,M1,M2,M3,M4,M5,M6,M7) \
        ACC8(rb, S0,S1,S2,S3,S4,S5,S6,S7, M0,M1,M2,M3,M4,M5,M6,M7) \
        ACC8(rc, S0,S1,S2,S3,S4,S5,S6,S7, M0,M1,M2,M3,M4,M5,M6,M7) \
        ACC8(rd, S0,S1,S2,S3,S4,S5,S6,S7, M0,M1,M2,M3,M4,M5,M6,M7) \
    } \
    if (kk + 3 < dd) { \
        PAIR_LOAD(vv, kk, ra) PAIR_LOAD(vv, kk + 2, rb) \
        ACC8(ra, S0,S1,S2,S3,S4,S5,S6,S7, M0,M1,M2,M3,M4,M5,M6,M7) \
        ACC8(rb, S0,S1,S2,S3,S4,S5,S6,S7, M0,M1,M2,M3,M4,M5,M6,M7) \
        kk += 4; \
    } \
    if (kk + 1 < dd) { \
        PAIR_LOAD(vv, kk, ra) \
        ACC8(ra, S0,S1,S2,S3,S4,S5,S6,S7, M0,M1,M2,M3,M4,M5,M6,M7) \
        kk += 2; \
    } \
    if (dd & 1) {                            /* single tail edge: lo half only */ \
        int ut = __builtin_amdgcn_readlane(vv, dd - 1); ut = (ut < NN) ? ut : 0; \
        short8 rt = *(const short8*)&x0b[(ut << 8) + fo8]; \
        if (!hi) { ACC8(rt, S0,S1,S2,S3,S4,S5,S6,S7, M0,M1,M2,M3,M4,M5,M6,M7) } \
    } \
    /* combine even/odd halves across the 32-lane boundary */ \
    { float o; \
      o=__shfl_xor(S0,32); S0+=o; o=__shfl_xor(S1,32); S1+=o; \
      o=__shfl_xor(S2,32); S2+=o; o=__shfl_xor(S3,32); S3+=o; \
      o=__shfl_xor(S4,32); S4+=o; o=__shfl_xor(S5,32); S5+=o; \
      o=__shfl_xor(S6,32); S6+=o; o=__shfl_xor(S7,32); S7+=o; \
      o=__shfl_xor(M0,32); M0=fmaxf(M0,o); o=__shfl_xor(M1,32); M1=fmaxf(M1,o); \
      o=__shfl_xor(M2,32); M2=fmaxf(M2,o); o=__shfl_xor(M3,32); M3=fmaxf(M3,o); \
      o=__shfl_xor(M4,32); M4=fmaxf(M4,o); o=__shfl_xor(M5,32); M5=fmaxf(M5,o); \
      o=__shfl_xor(M6,32); M6=fmaxf(M6,o); o=__shfl_xor(M7,32); M7=fmaxf(M7,o); } \
    if (!hi) { \
        float e0,e1,e2,e3,e4,e5,e6,e7, a0,a1,a2,a3,a4,a5,a6,a7; \
        if (dd > 0) { \
            float inv = 1.0f / (float)dd; \
            e0=S0*inv;e1=S1*inv;e2=S2*inv;e3=S3*inv;e4=S4*inv;e5=S5*inv;e6=S6*inv;e7=S7*inv; \
            a0=M0;a1=M1;a2=M2;a3=M3;a4=M4;a5=M5;a6=M6;a7=M7; \
        } else { \
            short8 rr = *(const short8*)&x0b[((nn) << 8) + fo8]; \
            e0=a0=bf2f(rr[0]); e1=a1=bf2f(rr[1]); e2=a2=bf2f(rr[2]); e3=a3=bf2f(rr[3]); \
            e4=a4=bf2f(rr[4]); e5=a5=bf2f(rr[5]); e6=a6=bf2f(rr[6]); e7=a7=bf2f(rr[7]); \
        } \
        int row = (q * 2 + (g)) * 2 + (l >> 4);      /* l<32: batch = l>>4 */ \
        int fb  = (l & 15) * 8; \
        short8 mv = { (short)f2bf(e0),(short)f2bf(e1),(short)f2bf(e2),(short)f2bf(e3), \
                      (short)f2bf(e4),(short)f2bf(e5),(short)f2bf(e6),(short)f2bf(e7) }; \
        short8 av = { (short)f2bf(a0),(short)f2bf(a1),(short)f2bf(a2),(short)f2bf(a3), \
                      (short)f2bf(a4),(short)f2bf(a5),(short)f2bf(a6),(short)f2bf(a7) }; \
        *(short8*)&xc[row * XCP + fb]       = mv; \
        *(short8*)&xc[row * XCP + 128 + fb] = av; \
    } \
}

    GATHER_NODE(vA, dA, nA, 0)
    GATHER_NODE(vB, dB, nB, 1)
#undef GATHER_NODE
#undef PAIR_LOAD
#undef ACC8
    __syncthreads();

    // ---- MFMA MLP: 16 rows x 128 cols; wave q owns 32 cols (2 tiles of 16) ----
    floatx4 acc[2];
#pragma unroll
    for (int ct = 0; ct < 2; ++ct) acc[ct] = (floatx4){0.f, 0.f, 0.f, 0.f};
#pragma unroll
    for (int ks = 0; ks < 8; ++ks) {
        short8 a = *(const short8*)&xc[m * XCP + ks * 32 + quad * 8];
#pragma unroll
        for (int ct = 0; ct < 2; ++ct) {
            short8 bfr = *(const short8*)&w0b[(colbase + ct * 16 + m) * 256 + ks * 32 + quad * 8];
            acc[ct] = __builtin_amdgcn_mfma_f32_16x16x32_bf16(a, bfr, acc[ct], 0, 0, 0);
        }
    }
#pragma unroll
    for (int ct = 0; ct < 2; ++ct) {
        int col = colbase + ct * 16 + m;
        float bias = b0[col];
#pragma unroll
        for (int r = 0; r < 4; ++r) {
            int row = quad * 4 + r;
            hs[row * HSP + col] = f2bf(fmaxf(acc[ct][r] + bias, 0.0f));
        }
    }
    __syncthreads();

    floatx4 acc2[2];
#pragma unroll
    for (int ct = 0; ct < 2; ++ct) acc2[ct] = (floatx4){0.f, 0.f, 0.f, 0.f};
#pragma unroll
    for (int ks = 0; ks < 4; ++ks) {
        short8 a = *(const short8*)&hs[m * HSP + ks * 32 + quad * 8];
#pragma unroll
        for (int ct = 0; ct < 2; ++ct) {
            short8 bfr = *(const short8*)&w1b[(colbase + ct * 16 + m) * 128 + ks * 32 + quad * 8];
            acc2[ct] = __builtin_amdgcn_mfma_f32_16x16x32_bf16(a, bfr, acc2[ct], 0, 0, 0);
        }
    }
    // Epilogue: residual from prefetched x0 registers, NT store (R5-proven mode)
#define EPI(ct, r, xv) { \
        int col = colbase + (ct) * 16 + m; \
        int row = quad * 4 + (r); \
        int n  = n0 + (row >> 1); \
        int b2 = row & 1; \
        int oi = (b2 * NN + n) * FF + col; \
        __builtin_nontemporal_store(xv + b1[col] + acc2[ct][r], &out[oi]); }
    EPI(0,0,xp0) EPI(0,1,xp1) EPI(0,2,xp2) EPI(0,3,xp3)
    EPI(1,0,xp4) EPI(1,1,xp5) EPI(1,2,xp6) EPI(1,3,xp7)
#undef EPI
}

extern "C" void kernel_launch(void* const* d_in, const int* in_sizes, int n_in,
                              void* d_out, int out_size, void* d_ws, size_t ws_size,
                              hipStream_t stream) {
    const float* x0  = (const float*)d_in[0];
    const int*   dst = (const int*)d_in[1];
    const int*   src = (const int*)d_in[2];
    const float* w0  = (const float*)d_in[3];
    const float* b0  = (const float*)d_in[4];
    const float* w1  = (const float*)d_in[5];
    const float* b1  = (const float*)d_in[6];
    float* out = (float*)d_out;
    int E = in_sizes[1];

    // ws layout: cursor (NN*CSTR ints) | esrc (NN*CAP ushort) | x0b | w0b | w1b
    int* cursor = (int*)d_ws;
    unsigned short* esrc = (unsigned short*)(cursor + (size_t)NN * CSTR);
    unsigned short* x0b  = esrc + (size_t)NN * CAP;
    unsigned short* w0b  = x0b + NBF2;
    unsigned short* w1b  = w0b + 128 * 256;

    int eb = (E + 255) / 256;

    (void)hipMemsetAsync(cursor, 0, (size_t)NN * CSTR * sizeof(int), stream);
    convert_fill<<<eb, 256, 0, stream>>>(dst, src, E, x0, w0, w1, cursor, esrc, x0b, w0b, w1b);
    fused_gcn<<<NN / NPB, 256, 0, stream>>>(x0b, x0, cursor, esrc, w0b, b0, w1b, b1, out);
}